// Round 1
// baseline (651.565 us; speedup 1.0000x reference)
//
#include <hip/hip_runtime.h>
#include <math.h>

#define B 8
#define N 4096
#define C 128
#define K 20
#define M (B*N)

__device__ __forceinline__ float lrelu(float x) { return x > 0.f ? x : 0.01f * x; }

// ---------------- weight prep: transpose to [c][o], fold scale factors ----------------
// wt layout: [0]=W1_blk0/21, [1]=W2_blk0/21, [2]=(W1+W2)_blk1/2, [3]=(W1+W2)_blk2/2  (each [c][o])
// bias: [0..C) = (b1_0 + 20*b2_0)/21 ; [C..2C) = (b1_1+b2_1)/2 ; [2C..3C) = (b1_2+b2_2)/2
__global__ void prep_w(const float* __restrict__ W1, const float* __restrict__ b1,
                       const float* __restrict__ W2, const float* __restrict__ b2,
                       float* __restrict__ wt, float* __restrict__ bias) {
    int t = blockIdx.x * blockDim.x + threadIdx.x;   // 0 .. C*C
    if (t < C * C) {
        int c = t / C, o = t % C;
        int oc = o * C + c;
        wt[0 * C * C + t] = W1[oc] * (1.f / 21.f);
        wt[1 * C * C + t] = W2[oc] * (1.f / 21.f);
        wt[2 * C * C + t] = (W1[1 * C * C + oc] + W2[1 * C * C + oc]) * 0.5f;
        wt[3 * C * C + t] = (W1[2 * C * C + oc] + W2[2 * C * C + oc]) * 0.5f;
    }
    if (t < C) {
        bias[t]         = (b1[t] + 20.f * b2[t]) * (1.f / 21.f);
        bias[C + t]     = (b1[C + t] + b2[C + t]) * 0.5f;
        bias[2 * C + t] = (b1[2 * C + t] + b2[2 * C + t]) * 0.5f;
    }
}

// ---------------- xyz -> (x,y,z,|x|^2) in point-major layout ----------------
__global__ void prep_xyz(const float* __restrict__ xyz, float4* __restrict__ xt) {
    int t = blockIdx.x * blockDim.x + threadIdx.x;   // B*N
    if (t >= B * N) return;
    int b = t >> 12, n = t & (N - 1);
    const float* p = xyz + (size_t)b * 3 * N;
    float x = p[n], y = p[N + n], z = p[2 * N + n];
    xt[t] = make_float4(x, y, z, x * x + y * y + z * z);
}

// ---------------- generic per-batch transpose [R][S] -> [S][R], 64x64 tiles ----------------
__global__ __launch_bounds__(256) void transpose_rs(const float* __restrict__ in,
                                                    float* __restrict__ out, int R, int S) {
    __shared__ float tile[64][65];
    int b = blockIdx.z;
    int r0 = blockIdx.y * 64, s0 = blockIdx.x * 64;
    const float* pin = in + (size_t)b * R * S;
    float* pout = out + (size_t)b * R * S;
    int tr = threadIdx.x >> 4;          // 0..15
    int ts = (threadIdx.x & 15) << 2;   // 0..60 step 4
#pragma unroll
    for (int i = 0; i < 4; ++i) {
        int r = tr + i * 16;
        float4 v = *(const float4*)&pin[(size_t)(r0 + r) * S + s0 + ts];
        tile[r][ts + 0] = v.x; tile[r][ts + 1] = v.y;
        tile[r][ts + 2] = v.z; tile[r][ts + 3] = v.w;
    }
    __syncthreads();
#pragma unroll
    for (int i = 0; i < 4; ++i) {
        int s = tr + i * 16;
        float4 v = make_float4(tile[ts + 0][s], tile[ts + 1][s], tile[ts + 2][s], tile[ts + 3][s]);
        *(float4*)&pout[(size_t)(s0 + s) * R + r0 + ts] = v;
    }
}

// ---------------- KNN: per row, indices of the 21 LARGEST distances; drop slot 0, keep 20 ----
__global__ __launch_bounds__(256) void knn_kernel(const float4* __restrict__ xt,
                                                  int* __restrict__ idx) {
    __shared__ float d[N];
    __shared__ float wm[4];
    __shared__ int   wi[4];
    int row = blockIdx.x;                 // 0 .. B*N
    int b = row >> 12, i = row & (N - 1);
    int tid = threadIdx.x;
    const float4* xb = xt + (size_t)b * N;
    float4 xi = xb[i];

    float lmax = -1e30f; int lidx = 0;
#pragma unroll 4
    for (int u = 0; u < 16; ++u) {
        int j = u * 256 + tid;
        float4 xj = xb[j];
        float dd = xi.w + xj.w - 2.f * (xi.x * xj.x + xi.y * xj.y + xi.z * xj.z);
        d[j] = dd;
        if (dd > lmax) { lmax = dd; lidx = j; }   // ascending j: strict > keeps lowest idx on tie
    }
    __syncthreads();

    int wid = tid >> 6, lane = tid & 63;
    for (int r = 0; r < K + 1; ++r) {
        // wave-level (max d, min idx) reduction
        float m = lmax; int mi = lidx;
#pragma unroll
        for (int off = 32; off; off >>= 1) {
            float om = __shfl_xor(m, off);
            int   oi = __shfl_xor(mi, off);
            if (om > m || (om == m && oi < mi)) { m = om; mi = oi; }
        }
        if (lane == 0) { wm[wid] = m; wi[wid] = mi; }
        __syncthreads();
        float gm = wm[0]; int gi = wi[0];
#pragma unroll
        for (int w = 1; w < 4; ++w) {
            float om = wm[w]; int oi = wi[w];
            if (om > gm || (om == gm && oi < gi)) { gm = om; gi = oi; }
        }
        if (r > 0 && tid == 0) idx[(size_t)row * K + (r - 1)] = gi;
        // owner marks extracted element and refreshes its cached local max
        if ((gi & 255) == tid) {
            d[gi] = -1e30f;
            lmax = -1e30f; lidx = 0;
#pragma unroll 4
            for (int u = 0; u < 16; ++u) {
                int j = u * 256 + tid;
                float dd = d[j];
                if (dd > lmax) { lmax = dd; lidx = j; }
            }
        }
        __syncthreads();
    }
}

// ---------------- gather-sum: sT[n][c] = sum_k lrelu(pt[idx[n][k]][c]) ----------------
__global__ __launch_bounds__(256) void gather_sum(const float* __restrict__ pt,
                                                  const int* __restrict__ idx,
                                                  float* __restrict__ sT) {
    int t = blockIdx.x * 256 + threadIdx.x;
    int pnt = t >> 5;                 // global point 0..B*N
    int c4 = (t & 31) << 2;           // channel (float4)
    int b = pnt >> 12;
    const float* pb = pt + (size_t)b * N * C;
    const int* ip = idx + (size_t)pnt * K;
    float4 acc = make_float4(0.f, 0.f, 0.f, 0.f);
#pragma unroll 4
    for (int k = 0; k < K; ++k) {
        int j = ip[k];
        float4 v = *(const float4*)&pb[(size_t)j * C + c4];
        acc.x += lrelu(v.x); acc.y += lrelu(v.y);
        acc.z += lrelu(v.z); acc.w += lrelu(v.w);
    }
    *(float4*)&sT[(size_t)pnt * C + c4] = acc;
}

// ---------------- fused GEMM: out = lrelu(A0)@Wt0 [+ A1@Wt1] + bias + shortcut --------------
// A*, shortcut, out: [M][C] row-major; Wt: [C][C] c-major ([c][o])
__global__ __launch_bounds__(256) void gemm_fused(const float* __restrict__ A0,
                                                  const float* __restrict__ A1,
                                                  const float* __restrict__ Wt0,
                                                  const float* __restrict__ Wt1,
                                                  const float* __restrict__ bias,
                                                  const float* __restrict__ shortcut,
                                                  float* __restrict__ out) {
    __shared__ float As[64][17];
    __shared__ float Ws[16][128];
    int row0 = blockIdx.x * 64;
    int tid = threadIdx.x;
    int r_ld = tid >> 2;               // 0..63
    int c_ld = (tid & 3) << 2;         // 0,4,8,12
    int r0 = (tid >> 4) << 2;          // 4 output rows
    int o0 = (tid & 15) << 2;          // output cols o0..o0+3 and o0+64..o0+67

    float acc[4][8];
#pragma unroll
    for (int j = 0; j < 4; ++j)
#pragma unroll
        for (int l = 0; l < 8; ++l) acc[j][l] = 0.f;

    for (int phase = 0; phase < 2; ++phase) {
        const float* A = phase ? A1 : A0;
        if (!A) break;
        const float* Wt = phase ? Wt1 : Wt0;
        for (int c0 = 0; c0 < C; c0 += 16) {
            float4 av = *(const float4*)&A[(size_t)(row0 + r_ld) * C + c0 + c_ld];
            if (phase == 0) {
                av.x = lrelu(av.x); av.y = lrelu(av.y);
                av.z = lrelu(av.z); av.w = lrelu(av.w);
            }
            As[r_ld][c_ld + 0] = av.x; As[r_ld][c_ld + 1] = av.y;
            As[r_ld][c_ld + 2] = av.z; As[r_ld][c_ld + 3] = av.w;
#pragma unroll
            for (int q = 0; q < 2; ++q) {
                int slot = tid + q * 256;            // 0..511
                int kk = slot >> 5;                  // 0..15
                int oo = (slot & 31) << 2;
                *(float4*)&Ws[kk][oo] = *(const float4*)&Wt[(size_t)(c0 + kk) * C + oo];
            }
            __syncthreads();
#pragma unroll
            for (int kk = 0; kk < 16; ++kk) {
                float a0 = As[r0 + 0][kk], a1 = As[r0 + 1][kk];
                float a2 = As[r0 + 2][kk], a3 = As[r0 + 3][kk];
                float4 w0 = *(const float4*)&Ws[kk][o0];
                float4 w1 = *(const float4*)&Ws[kk][o0 + 64];
                acc[0][0] += a0 * w0.x; acc[0][1] += a0 * w0.y; acc[0][2] += a0 * w0.z; acc[0][3] += a0 * w0.w;
                acc[0][4] += a0 * w1.x; acc[0][5] += a0 * w1.y; acc[0][6] += a0 * w1.z; acc[0][7] += a0 * w1.w;
                acc[1][0] += a1 * w0.x; acc[1][1] += a1 * w0.y; acc[1][2] += a1 * w0.z; acc[1][3] += a1 * w0.w;
                acc[1][4] += a1 * w1.x; acc[1][5] += a1 * w1.y; acc[1][6] += a1 * w1.z; acc[1][7] += a1 * w1.w;
                acc[2][0] += a2 * w0.x; acc[2][1] += a2 * w0.y; acc[2][2] += a2 * w0.z; acc[2][3] += a2 * w0.w;
                acc[2][4] += a2 * w1.x; acc[2][5] += a2 * w1.y; acc[2][6] += a2 * w1.z; acc[2][7] += a2 * w1.w;
                acc[3][0] += a3 * w0.x; acc[3][1] += a3 * w0.y; acc[3][2] += a3 * w0.z; acc[3][3] += a3 * w0.w;
                acc[3][4] += a3 * w1.x; acc[3][5] += a3 * w1.y; acc[3][6] += a3 * w1.z; acc[3][7] += a3 * w1.w;
            }
            __syncthreads();
        }
    }

    float4 bb0 = *(const float4*)&bias[o0];
    float4 bb1 = *(const float4*)&bias[o0 + 64];
#pragma unroll
    for (int j = 0; j < 4; ++j) {
        size_t r = (size_t)(row0 + r0 + j);
        float4 s0 = *(const float4*)&shortcut[r * C + o0];
        float4 s1 = *(const float4*)&shortcut[r * C + o0 + 64];
        float4 v0 = make_float4(acc[j][0] + bb0.x + s0.x, acc[j][1] + bb0.y + s0.y,
                                acc[j][2] + bb0.z + s0.z, acc[j][3] + bb0.w + s0.w);
        float4 v1 = make_float4(acc[j][4] + bb1.x + s1.x, acc[j][5] + bb1.y + s1.y,
                                acc[j][6] + bb1.z + s1.z, acc[j][7] + bb1.w + s1.w);
        *(float4*)&out[r * C + o0] = v0;
        *(float4*)&out[r * C + o0 + 64] = v1;
    }
}

extern "C" void kernel_launch(void* const* d_in, const int* in_sizes, int n_in,
                              void* d_out, int out_size, void* d_ws, size_t ws_size,
                              hipStream_t stream) {
    const float* xyz    = (const float*)d_in[0];
    const float* points = (const float*)d_in[1];
    const float* W1     = (const float*)d_in[2];
    const float* b1     = (const float*)d_in[3];
    const float* W2     = (const float*)d_in[4];
    const float* b2     = (const float*)d_in[5];

    float* ws = (float*)d_ws;
    float4* xt  = (float4*)ws;                 // B*N float4
    float* pt_a = ws + (size_t)B * N * 4;      // [M][C]
    float* pt_b = pt_a + (size_t)M * C;
    float* sT   = pt_b + (size_t)M * C;
    float* wt   = sT + (size_t)M * C;          // 4*C*C
    float* bias = wt + 4 * C * C;              // 3*C
    int*   idx  = (int*)(bias + 3 * C);        // [M][K]

    prep_w<<<(C * C + 255) / 256, 256, 0, stream>>>(W1, b1, W2, b2, wt, bias);
    prep_xyz<<<(B * N + 255) / 256, 256, 0, stream>>>(xyz, xt);
    {
        dim3 g(N / 64, C / 64, B);
        transpose_rs<<<g, 256, 0, stream>>>(points, pt_a, C, N);   // [C][N] -> [N][C]
    }
    knn_kernel<<<B * N, 256, 0, stream>>>(xt, idx);
    gather_sum<<<(M * 32) / 256, 256, 0, stream>>>(pt_a, idx, sT);
    // block 0: dual GEMM (lrelu(pt_a)@W1' + sT@W2') + bias0 + pt_a
    gemm_fused<<<M / 64, 256, 0, stream>>>(pt_a, sT, wt, wt + C * C, bias, pt_a, pt_b);
    // block 1
    gemm_fused<<<M / 64, 256, 0, stream>>>(pt_b, nullptr, wt + 2 * C * C, nullptr, bias + C, pt_b, pt_a);
    // block 2
    gemm_fused<<<M / 64, 256, 0, stream>>>(pt_a, nullptr, wt + 3 * C * C, nullptr, bias + 2 * C, pt_a, pt_b);
    {
        dim3 g(C / 64, N / 64, B);
        transpose_rs<<<g, 256, 0, stream>>>(pt_b, (float*)d_out, N, C);  // [N][C] -> [C][N]
    }
}

// Round 2
// 218.839 us; speedup vs baseline: 2.9774x; 2.9774x over previous
//
#include <hip/hip_runtime.h>
#include <math.h>

#define B 8
#define N 4096
#define C 128
#define K 20
#define M (B*N)

__device__ __forceinline__ float lrelu(float x) { return x > 0.f ? x : 0.01f * x; }

// ---------------- weight prep: transpose to [c][o], fold scale factors ----------------
__global__ void prep_w(const float* __restrict__ W1, const float* __restrict__ b1,
                       const float* __restrict__ W2, const float* __restrict__ b2,
                       float* __restrict__ wt, float* __restrict__ bias) {
    int t = blockIdx.x * blockDim.x + threadIdx.x;   // 0 .. C*C
    if (t < C * C) {
        int c = t / C, o = t % C;
        int oc = o * C + c;
        wt[0 * C * C + t] = W1[oc] * (1.f / 21.f);
        wt[1 * C * C + t] = W2[oc] * (1.f / 21.f);
        wt[2 * C * C + t] = (W1[1 * C * C + oc] + W2[1 * C * C + oc]) * 0.5f;
        wt[3 * C * C + t] = (W1[2 * C * C + oc] + W2[2 * C * C + oc]) * 0.5f;
    }
    if (t < C) {
        bias[t]         = (b1[t] + 20.f * b2[t]) * (1.f / 21.f);
        bias[C + t]     = (b1[C + t] + b2[C + t]) * 0.5f;
        bias[2 * C + t] = (b1[2 * C + t] + b2[2 * C + t]) * 0.5f;
    }
}

// ---------------- xyz -> (x,y,z,|x|^2) in point-major layout ----------------
__global__ void prep_xyz(const float* __restrict__ xyz, float4* __restrict__ xt) {
    int t = blockIdx.x * blockDim.x + threadIdx.x;   // B*N
    if (t >= B * N) return;
    int b = t >> 12, n = t & (N - 1);
    const float* p = xyz + (size_t)b * 3 * N;
    float x = p[n], y = p[N + n], z = p[2 * N + n];
    xt[t] = make_float4(x, y, z, x * x + y * y + z * z);
}

// ---------------- generic per-batch transpose [R][S] -> [S][R], 64x64 tiles ----------------
__global__ __launch_bounds__(256) void transpose_rs(const float* __restrict__ in,
                                                    float* __restrict__ out, int R, int S) {
    __shared__ float tile[64][65];
    int b = blockIdx.z;
    int r0 = blockIdx.y * 64, s0 = blockIdx.x * 64;
    const float* pin = in + (size_t)b * R * S;
    float* pout = out + (size_t)b * R * S;
    int tr = threadIdx.x >> 4;          // 0..15
    int ts = (threadIdx.x & 15) << 2;   // 0..60 step 4
#pragma unroll
    for (int i = 0; i < 4; ++i) {
        int r = tr + i * 16;
        float4 v = *(const float4*)&pin[(size_t)(r0 + r) * S + s0 + ts];
        tile[r][ts + 0] = v.x; tile[r][ts + 1] = v.y;
        tile[r][ts + 2] = v.z; tile[r][ts + 3] = v.w;
    }
    __syncthreads();
#pragma unroll
    for (int i = 0; i < 4; ++i) {
        int s = tr + i * 16;
        float4 v = make_float4(tile[ts + 0][s], tile[ts + 1][s], tile[ts + 2][s], tile[ts + 3][s]);
        *(float4*)&pout[(size_t)(s0 + s) * R + r0 + ts] = v;
    }
}

// ---------------- KNN via bisection-threshold selection ----------------
// 4 rows per 256-thread block; thread owns j-slice {u*256+tid} for all 4 rows.
// Find per-row threshold t with count(d > t) in [21, 96] via value bisection
// (exponential distance tail -> ~2-4 iterations), compact candidates, exact
// all-pairs rank on u64 keys (bits(d)<<32 | ~idx) => top_k tie-break (lower
// index first) reproduced exactly. Rank 0 (largest) dropped, ranks 1..20 kept.
__global__ __launch_bounds__(256, 4) void knn_kernel(const float4* __restrict__ xt,
                                                     int* __restrict__ idx) {
    __shared__ unsigned int wred[4][2];            // per-wave packed count partials
    __shared__ float maxred[4][4];                 // [wave][row] max partials
    __shared__ unsigned int cnt[4];
    __shared__ unsigned long long cand[4][128];

    int tid = threadIdx.x;
    int wid = tid >> 6, lane = tid & 63;
    int blk = blockIdx.x;                          // 0 .. 8191
    int b = blk >> 10;                             // 1024 blocks per batch
    int i0 = (blk & 1023) << 2;                    // base row in batch
    const float4* xb = xt + (size_t)b * N;

    float4 xi[4];
#pragma unroll
    for (int r = 0; r < 4; ++r) xi[r] = xb[i0 + r];

    if (tid < 4) cnt[tid] = 0;

    float d[4][16];
    float mx[4] = {-1e30f, -1e30f, -1e30f, -1e30f};
#pragma unroll
    for (int u = 0; u < 16; ++u) {
        float4 xj = xb[u * 256 + tid];
#pragma unroll
        for (int r = 0; r < 4; ++r) {
            float dd = xi[r].w + xj.w - 2.f * (xi[r].x * xj.x + xi[r].y * xj.y + xi[r].z * xj.z);
            d[r][u] = dd;
            mx[r] = fmaxf(mx[r], dd);
        }
    }
    // block-wide per-row max
#pragma unroll
    for (int off = 32; off; off >>= 1) {
#pragma unroll
        for (int r = 0; r < 4; ++r) mx[r] = fmaxf(mx[r], __shfl_xor(mx[r], off));
    }
    if (lane == 0) {
#pragma unroll
        for (int r = 0; r < 4; ++r) maxred[wid][r] = mx[r];
    }
    __syncthreads();

    float lo[4], hi[4], thr[4];
    bool done[4];
#pragma unroll
    for (int r = 0; r < 4; ++r) {
        hi[r] = fmaxf(fmaxf(maxred[0][r], maxred[1][r]), fmaxf(maxred[2][r], maxred[3][r]));
        lo[r] = 0.f;
        thr[r] = 0.f;
        done[r] = false;
    }

    for (int it = 0; it < 20; ++it) {
        if (done[0] && done[1] && done[2] && done[3]) break;
#pragma unroll
        for (int r = 0; r < 4; ++r) if (!done[r]) thr[r] = 0.5f * (lo[r] + hi[r]);
        unsigned int c[4] = {0u, 0u, 0u, 0u};
#pragma unroll
        for (int u = 0; u < 16; ++u) {
#pragma unroll
            for (int r = 0; r < 4; ++r) c[r] += (d[r][u] > thr[r]) ? 1u : 0u;
        }
        unsigned int p01 = c[0] | (c[1] << 16);
        unsigned int p23 = c[2] | (c[3] << 16);
#pragma unroll
        for (int off = 32; off; off >>= 1) {
            p01 += __shfl_xor(p01, off);
            p23 += __shfl_xor(p23, off);
        }
        if (lane == 0) { wred[wid][0] = p01; wred[wid][1] = p23; }
        __syncthreads();
        unsigned int s01 = wred[0][0] + wred[1][0] + wred[2][0] + wred[3][0];
        unsigned int s23 = wred[0][1] + wred[1][1] + wred[2][1] + wred[3][1];
        unsigned int cc[4] = { s01 & 0xFFFFu, s01 >> 16, s23 & 0xFFFFu, s23 >> 16 };
#pragma unroll
        for (int r = 0; r < 4; ++r) {
            if (!done[r]) {
                if (cc[r] >= (unsigned)(K + 1) && cc[r] <= 96u) done[r] = true;
                else if (cc[r] > 96u) lo[r] = thr[r];
                else hi[r] = thr[r];
            }
        }
        __syncthreads();   // protect wred for next iteration
    }
#pragma unroll
    for (int r = 0; r < 4; ++r) if (!done[r]) thr[r] = lo[r];  // count(>lo) >= 21 invariant

    // compact candidates
#pragma unroll
    for (int u = 0; u < 16; ++u) {
#pragma unroll
        for (int r = 0; r < 4; ++r) {
            float dd = d[r][u];
            if (dd > thr[r]) {
                unsigned int pos = atomicAdd(&cnt[r], 1u);
                if (pos < 128u) {
                    unsigned int j = (unsigned)(u * 256 + tid);
                    cand[r][pos] = ((unsigned long long)__float_as_uint(dd) << 32) | (unsigned)(~j);
                }
            }
        }
    }
    __syncthreads();

    // exact rank among candidates; wave wid handles row wid
    {
        int r = wid;
        unsigned int c = cnt[r]; if (c > 128u) c = 128u;
        for (int s = lane; s < (int)c; s += 64) {
            unsigned long long my = cand[r][s];
            int rank = 0;
            for (int q = 0; q < (int)c; ++q) rank += (cand[r][q] > my) ? 1 : 0;
            if (rank >= 1 && rank <= K) {
                int row = (b << 12) + i0 + r;
                idx[(size_t)row * K + (rank - 1)] = (int)(~(unsigned int)my);
            }
        }
    }
}

// ---------------- gather-sum: sT[n][c] = sum_k lrelu(pt[idx[n][k]][c]) ----------------
__global__ __launch_bounds__(256) void gather_sum(const float* __restrict__ pt,
                                                  const int* __restrict__ idx,
                                                  float* __restrict__ sT) {
    int t = blockIdx.x * 256 + threadIdx.x;
    int pnt = t >> 5;                 // global point 0..B*N
    int c4 = (t & 31) << 2;           // channel (float4)
    int b = pnt >> 12;
    const float* pb = pt + (size_t)b * N * C;
    const int* ip = idx + (size_t)pnt * K;
    float4 acc = make_float4(0.f, 0.f, 0.f, 0.f);
#pragma unroll 4
    for (int k = 0; k < K; ++k) {
        int j = ip[k];
        float4 v = *(const float4*)&pb[(size_t)j * C + c4];
        acc.x += lrelu(v.x); acc.y += lrelu(v.y);
        acc.z += lrelu(v.z); acc.w += lrelu(v.w);
    }
    *(float4*)&sT[(size_t)pnt * C + c4] = acc;
}

// ---------------- fused GEMM: out = lrelu(A0)@Wt0 [+ A1@Wt1] + bias + shortcut --------------
__global__ __launch_bounds__(256) void gemm_fused(const float* __restrict__ A0,
                                                  const float* __restrict__ A1,
                                                  const float* __restrict__ Wt0,
                                                  const float* __restrict__ Wt1,
                                                  const float* __restrict__ bias,
                                                  const float* __restrict__ shortcut,
                                                  float* __restrict__ out) {
    __shared__ float As[64][17];
    __shared__ float Ws[16][128];
    int row0 = blockIdx.x * 64;
    int tid = threadIdx.x;
    int r_ld = tid >> 2;               // 0..63
    int c_ld = (tid & 3) << 2;         // 0,4,8,12
    int r0 = (tid >> 4) << 2;          // 4 output rows
    int o0 = (tid & 15) << 2;          // output cols o0..o0+3 and o0+64..o0+67

    float acc[4][8];
#pragma unroll
    for (int j = 0; j < 4; ++j)
#pragma unroll
        for (int l = 0; l < 8; ++l) acc[j][l] = 0.f;

    for (int phase = 0; phase < 2; ++phase) {
        const float* A = phase ? A1 : A0;
        if (!A) break;
        const float* Wt = phase ? Wt1 : Wt0;
        for (int c0 = 0; c0 < C; c0 += 16) {
            float4 av = *(const float4*)&A[(size_t)(row0 + r_ld) * C + c0 + c_ld];
            if (phase == 0) {
                av.x = lrelu(av.x); av.y = lrelu(av.y);
                av.z = lrelu(av.z); av.w = lrelu(av.w);
            }
            As[r_ld][c_ld + 0] = av.x; As[r_ld][c_ld + 1] = av.y;
            As[r_ld][c_ld + 2] = av.z; As[r_ld][c_ld + 3] = av.w;
#pragma unroll
            for (int q = 0; q < 2; ++q) {
                int slot = tid + q * 256;            // 0..511
                int kk = slot >> 5;                  // 0..15
                int oo = (slot & 31) << 2;
                *(float4*)&Ws[kk][oo] = *(const float4*)&Wt[(size_t)(c0 + kk) * C + oo];
            }
            __syncthreads();
#pragma unroll
            for (int kk = 0; kk < 16; ++kk) {
                float a0 = As[r0 + 0][kk], a1 = As[r0 + 1][kk];
                float a2 = As[r0 + 2][kk], a3 = As[r0 + 3][kk];
                float4 w0 = *(const float4*)&Ws[kk][o0];
                float4 w1 = *(const float4*)&Ws[kk][o0 + 64];
                acc[0][0] += a0 * w0.x; acc[0][1] += a0 * w0.y; acc[0][2] += a0 * w0.z; acc[0][3] += a0 * w0.w;
                acc[0][4] += a0 * w1.x; acc[0][5] += a0 * w1.y; acc[0][6] += a0 * w1.z; acc[0][7] += a0 * w1.w;
                acc[1][0] += a1 * w0.x; acc[1][1] += a1 * w0.y; acc[1][2] += a1 * w0.z; acc[1][3] += a1 * w0.w;
                acc[1][4] += a1 * w1.x; acc[1][5] += a1 * w1.y; acc[1][6] += a1 * w1.z; acc[1][7] += a1 * w1.w;
                acc[2][0] += a2 * w0.x; acc[2][1] += a2 * w0.y; acc[2][2] += a2 * w0.z; acc[2][3] += a2 * w0.w;
                acc[2][4] += a2 * w1.x; acc[2][5] += a2 * w1.y; acc[2][6] += a2 * w1.z; acc[2][7] += a2 * w1.w;
                acc[3][0] += a3 * w0.x; acc[3][1] += a3 * w0.y; acc[3][2] += a3 * w0.z; acc[3][3] += a3 * w0.w;
                acc[3][4] += a3 * w1.x; acc[3][5] += a3 * w1.y; acc[3][6] += a3 * w1.z; acc[3][7] += a3 * w1.w;
            }
            __syncthreads();
        }
    }

    float4 bb0 = *(const float4*)&bias[o0];
    float4 bb1 = *(const float4*)&bias[o0 + 64];
#pragma unroll
    for (int j = 0; j < 4; ++j) {
        size_t r = (size_t)(row0 + r0 + j);
        float4 s0 = *(const float4*)&shortcut[r * C + o0];
        float4 s1 = *(const float4*)&shortcut[r * C + o0 + 64];
        float4 v0 = make_float4(acc[j][0] + bb0.x + s0.x, acc[j][1] + bb0.y + s0.y,
                                acc[j][2] + bb0.z + s0.z, acc[j][3] + bb0.w + s0.w);
        float4 v1 = make_float4(acc[j][4] + bb1.x + s1.x, acc[j][5] + bb1.y + s1.y,
                                acc[j][6] + bb1.z + s1.z, acc[j][7] + bb1.w + s1.w);
        *(float4*)&out[r * C + o0] = v0;
        *(float4*)&out[r * C + o0 + 64] = v1;
    }
}

extern "C" void kernel_launch(void* const* d_in, const int* in_sizes, int n_in,
                              void* d_out, int out_size, void* d_ws, size_t ws_size,
                              hipStream_t stream) {
    const float* xyz    = (const float*)d_in[0];
    const float* points = (const float*)d_in[1];
    const float* W1     = (const float*)d_in[2];
    const float* b1     = (const float*)d_in[3];
    const float* W2     = (const float*)d_in[4];
    const float* b2     = (const float*)d_in[5];

    float* ws = (float*)d_ws;
    float4* xt  = (float4*)ws;                 // B*N float4
    float* pt_a = ws + (size_t)B * N * 4;      // [M][C]
    float* pt_b = pt_a + (size_t)M * C;
    float* sT   = pt_b + (size_t)M * C;
    float* wt   = sT + (size_t)M * C;          // 4*C*C
    float* bias = wt + 4 * C * C;              // 3*C
    int*   idx  = (int*)(bias + 3 * C);        // [M][K]

    prep_w<<<(C * C + 255) / 256, 256, 0, stream>>>(W1, b1, W2, b2, wt, bias);
    prep_xyz<<<(B * N + 255) / 256, 256, 0, stream>>>(xyz, xt);
    {
        dim3 g(N / 64, C / 64, B);
        transpose_rs<<<g, 256, 0, stream>>>(points, pt_a, C, N);   // [C][N] -> [N][C]
    }
    knn_kernel<<<M / 4, 256, 0, stream>>>(xt, idx);
    gather_sum<<<(M * 32) / 256, 256, 0, stream>>>(pt_a, idx, sT);
    // block 0: dual GEMM (lrelu(pt_a)@W1' + sT@W2') + bias0 + pt_a
    gemm_fused<<<M / 64, 256, 0, stream>>>(pt_a, sT, wt, wt + C * C, bias, pt_a, pt_b);
    // block 1
    gemm_fused<<<M / 64, 256, 0, stream>>>(pt_b, nullptr, wt + 2 * C * C, nullptr, bias + C, pt_b, pt_a);
    // block 2
    gemm_fused<<<M / 64, 256, 0, stream>>>(pt_a, nullptr, wt + 3 * C * C, nullptr, bias + 2 * C, pt_a, pt_b);
    {
        dim3 g(C / 64, N / 64, B);
        transpose_rs<<<g, 256, 0, stream>>>(pt_b, (float*)d_out, N, C);  // [N][C] -> [C][N]
    }
}